// Round 2
// baseline (1427.155 us; speedup 1.0000x reference)
//
#include <hip/hip_runtime.h>
#include <stdint.h>

typedef unsigned short u16;
typedef float f32x4 __attribute__((ext_vector_type(4)));
typedef __bf16 v8bf __attribute__((ext_vector_type(8)));

static __device__ __forceinline__ float bf2f(u16 u) {
  union { uint32_t i; float f; } v; v.i = ((uint32_t)u) << 16; return v.f;
}
static __device__ __forceinline__ u16 f2bf(float f) {
  union { float f; uint32_t i; } v; v.f = f;
  uint32_t b = v.i;
  return (u16)((b + 0x7FFFu + ((b >> 16) & 1u)) >> 16);
}

// ---------------- K1: LayerNorm over C=96 (fp32 in) -> bf16 xn ----------------
// 64 voxels/block, 4 threads per voxel (24 ch each).
__global__ __launch_bounds__(256) void k_ln(const float* __restrict__ x,
                                            const float* __restrict__ gamma,
                                            const float* __restrict__ beta,
                                            u16* __restrict__ xn) {
  int tid = threadIdx.x;
  int vox = blockIdx.x * 64 + (tid >> 2);
  int q = tid & 3;
  const float4* px = (const float4*)(x + (size_t)vox * 96 + q * 24);
  float f[24];
  *(float4*)&f[0]  = px[0]; *(float4*)&f[4]  = px[1]; *(float4*)&f[8]  = px[2];
  *(float4*)&f[12] = px[3]; *(float4*)&f[16] = px[4]; *(float4*)&f[20] = px[5];
  float s = 0.f, s2 = 0.f;
#pragma unroll
  for (int i = 0; i < 24; ++i) { s += f[i]; s2 += f[i] * f[i]; }
  s += __shfl_xor(s, 1);  s += __shfl_xor(s, 2);
  s2 += __shfl_xor(s2, 1); s2 += __shfl_xor(s2, 2);
  float mu = s * (1.f / 96.f);
  float var = s2 * (1.f / 96.f) - mu * mu;
  float rs = rsqrtf(var + 1e-5f);
  uint32_t ow[12];
#pragma unroll
  for (int i = 0; i < 12; ++i) {
    int c0 = q * 24 + 2 * i;
    float v0 = (f[2 * i]     - mu) * rs * gamma[c0]     + beta[c0];
    float v1 = (f[2 * i + 1] - mu) * rs * gamma[c0 + 1] + beta[c0 + 1];
    ow[i] = (uint32_t)f2bf(v0) | ((uint32_t)f2bf(v1) << 16);
  }
  uint4* po = (uint4*)(xn + (size_t)vox * 96 + q * 24);
  po[0] = *(uint4*)&ow[0]; po[1] = *(uint4*)&ow[4]; po[2] = *(uint4*)&ow[8];
}

// ---------------- K2: repack qkv_w (fp32) into bf16 MFMA B-fragment layout ----------------
// Wb[tap][ks][nt][lane][j] : value = W[tap][ci=ks*32+(lane>>4)*8+j][co=nt*16+(lane&15)]
__global__ __launch_bounds__(256) void k_repack(const float* __restrict__ qw,
                                                u16* __restrict__ Wb) {
  int t = blockIdx.x * 256 + threadIdx.x;
  if (t >= 27 * 3 * 18 * 64) return;
  int l = t & 63;
  int rest = t >> 6;
  int nt = rest % 18;
  int ks = (rest / 18) % 3;
  int tap = rest / 54;
  int co = nt * 16 + (l & 15);
  int cibase = ks * 32 + (l >> 4) * 8;
  u16 vals[8];
#pragma unroll
  for (int j = 0; j < 8; ++j)
    vals[j] = f2bf(qw[((size_t)tap * 96 + cibase + j) * 288 + co]);
  *(uint4*)(Wb + (size_t)t * 8) = *(uint4*)vals;
}

// ---------------- K0: zero scratch floats ----------------
__global__ __launch_bounds__(256) void k_zero(float* p, int n) {
  int i = blockIdx.x * 256 + threadIdx.x;
  if (i < n) p[i] = 0.f;
}

// ---------------- K3: conv3d 3x3x3 96->288 via MFMA bf16 ----------------
// Block = one (x0,y0) z-column of 64 voxels, all 288 out channels.
// 4 waves in 2x2 grid: wave tile 32 rows x 144 cols.
__global__ __launch_bounds__(256, 2) void k_conv(const u16* __restrict__ xn,
                                                 const u16* __restrict__ Wb,
                                                 const float* __restrict__ qkvb,
                                                 u16* __restrict__ y) {
  __shared__ u16 As[66 * 104];     // pitch 104 u16 = 208 B
  __shared__ u16 Bs[3456 * 8];     // one tap in fragment layout
  int tid = threadIdx.x;
  int x0 = blockIdx.x >> 6, y0 = blockIdx.x & 63;
  int lane = tid & 63, w = tid >> 6;
  int wr = w >> 1, wc = w & 1;

  f32x4 acc[2][9];
#pragma unroll
  for (int m = 0; m < 2; ++m)
#pragma unroll
    for (int n = 0; n < 9; ++n) acc[m][n] = (f32x4)0.f;

  for (int dxy = 0; dxy < 9; ++dxy) {
    int dx = dxy / 3, dy = dxy % 3;
    int xx = x0 + dx - 1, yy = y0 + dy - 1;
    bool colok = ((unsigned)xx < 64u) && ((unsigned)yy < 64u);
    for (int dz = 0; dz < 3; ++dz) {
      __syncthreads();
      if (dz == 0) {
        const uint4* src = (const uint4*)(xn + ((size_t)(xx * 64 + yy) * 64) * 96);
        for (int i = tid; i < 66 * 12; i += 256) {
          int row = i / 12, c8 = i - row * 12;
          uint4 v = make_uint4(0u, 0u, 0u, 0u);
          if (colok && row >= 1 && row <= 64) v = src[(row - 1) * 12 + c8];
          *(uint4*)&As[row * 104 + c8 * 8] = v;
        }
      }
      int tap = dxy * 3 + dz;
      const uint4* wsrc = (const uint4*)(Wb + (size_t)tap * 27648);
      uint4* bdst = (uint4*)Bs;
      for (int i = tid; i < 3456; i += 256) bdst[i] = wsrc[i];
      __syncthreads();

#pragma unroll
      for (int ks = 0; ks < 3; ++ks) {
        int ar = wr * 32 + (lane & 15) + dz;
        int ac = ks * 32 + (lane >> 4) * 8;
        v8bf a0 = *(const v8bf*)&As[ar * 104 + ac];
        v8bf a1 = *(const v8bf*)&As[(ar + 16) * 104 + ac];
#pragma unroll
        for (int nt = 0; nt < 9; ++nt) {
          v8bf b = *(const v8bf*)&Bs[((ks * 18 + wc * 9 + nt) * 64 + lane) * 8];
          acc[0][nt] = __builtin_amdgcn_mfma_f32_16x16x32_bf16(a0, b, acc[0][nt], 0, 0, 0);
          acc[1][nt] = __builtin_amdgcn_mfma_f32_16x16x32_bf16(a1, b, acc[1][nt], 0, 0, 0);
        }
      }
    }
  }

  size_t voxbase = (size_t)(x0 * 64 + y0) * 64;
#pragma unroll
  for (int m = 0; m < 2; ++m)
#pragma unroll
    for (int nt = 0; nt < 9; ++nt) {
      int col = wc * 144 + nt * 16 + (lane & 15);
      float bias = qkvb[col];
#pragma unroll
      for (int r = 0; r < 4; ++r) {
        int vrow = wr * 32 + m * 16 + (lane >> 4) * 4 + r;
        y[(voxbase + vrow) * 288 + col] = f2bf(acc[m][nt][r] + bias);
      }
    }
}

// ---------------- K4: Gram S[f,h,c,d] = sum_g q.k, plus norms ----------------
__global__ __launch_bounds__(256) void k_gram(const u16* __restrict__ y,
                                              float* __restrict__ S,
                                              float* __restrict__ qn2,
                                              float* __restrict__ kn2) {
  __shared__ u16 qk[8 * 192];
  int tid = threadIdx.x;
  int f = blockIdx.x >> 4, chunk = blockIdx.x & 15;
  int fx = f >> 4, fy = (f >> 2) & 3, fz = f & 3;
  int h = tid >> 6;
  int e0 = tid * 9;
  int ci[9], di[9];
#pragma unroll
  for (int i = 0; i < 9; ++i) {
    int rem = (e0 + i) % 576;
    ci[i] = rem / 24; di[i] = rem % 24;
  }
  float cacc[9];
#pragma unroll
  for (int i = 0; i < 9; ++i) cacc[i] = 0.f;
  float nacc = 0.f;

  for (int grp = 0; grp < 32; ++grp) {
    __syncthreads();
    for (int i = tid; i < 192; i += 256) {
      int rr = i / 24, c8 = i - rr * 24;
      int g = chunk * 256 + grp * 8 + rr;
      int gx = g >> 8, gy = (g >> 4) & 15, gz = g & 15;
      size_t vox = ((size_t)(gx * 4 + fx) * 64 + (gy * 4 + fy)) * 64 + (gz * 4 + fz);
      *(uint4*)&qk[rr * 192 + c8 * 8] = *(const uint4*)(y + vox * 288 + c8 * 8);
    }
    __syncthreads();
#pragma unroll 2
    for (int r = 0; r < 8; ++r) {
      const u16* row = &qk[r * 192];
#pragma unroll
      for (int i = 0; i < 9; ++i) {
        float qv = bf2f(row[h * 24 + ci[i]]);
        float kv = bf2f(row[96 + h * 24 + di[i]]);
        cacc[i] += qv * kv;
      }
      if (tid < 192) { float v = bf2f(row[tid]); nacc += v * v; }
    }
  }
  float* Sf = S + (size_t)f * 2304;
#pragma unroll
  for (int i = 0; i < 9; ++i) atomicAdd(&Sf[e0 + i], cacc[i]);
  if (tid < 96) atomicAdd(&qn2[f * 96 + tid], nacc);
  else if (tid < 192) atomicAdd(&kn2[f * 96 + tid - 96], nacc);
}

// ---------------- K5: normalize + softmax + fold out_w -> Mt[f][j][c'] (bf16) ----------------
__global__ __launch_bounds__(256) void k_attn(const float* __restrict__ S,
                                              const float* __restrict__ qn2,
                                              const float* __restrict__ kn2,
                                              const float* __restrict__ out_w,
                                              const float* __restrict__ temp,
                                              u16* __restrict__ Mt) {
  __shared__ float attn[2304];
  __shared__ float invq[96], invk[96];
  __shared__ float ow[9216];
  int tid = threadIdx.x;
  int f = blockIdx.x;
  if (tid < 96) {
    invq[tid] = 1.f / fmaxf(sqrtf(qn2[f * 96 + tid]), 1e-12f);
    invk[tid] = 1.f / fmaxf(sqrtf(kn2[f * 96 + tid]), 1e-12f);
  }
  for (int i = tid; i < 9216; i += 256) ow[i] = out_w[i];
  __syncthreads();
  if (tid < 96) {
    int h = tid / 24, c = tid % 24;
    float tmp = temp[h];
    const float* Sr = S + (size_t)f * 2304 + (size_t)h * 576 + c * 24;
    float lg[24];
    float mx = -1e30f;
#pragma unroll
    for (int d = 0; d < 24; ++d) {
      lg[d] = Sr[d] * invq[tid] * invk[h * 24 + d] * tmp;
      mx = fmaxf(mx, lg[d]);
    }
    float sum = 0.f;
#pragma unroll
    for (int d = 0; d < 24; ++d) { lg[d] = __expf(lg[d] - mx); sum += lg[d]; }
    float inv = 1.f / sum;
#pragma unroll
    for (int d = 0; d < 24; ++d) attn[h * 576 + c * 24 + d] = lg[d] * inv;
  }
  __syncthreads();
  for (int o = tid; o < 9216; o += 256) {
    int j = o / 96, cp = o - j * 96;
    int h2 = j / 24, d = j % 24;
    float s = 0.f;
#pragma unroll
    for (int cc = 0; cc < 24; ++cc)
      s += attn[h2 * 576 + cc * 24 + d] * ow[cp * 96 + h2 * 24 + cc];
    Mt[(size_t)f * 9216 + o] = f2bf(s);
  }
}

// ---------------- K6: out = Mt[f] @ v + out_b + x (residual), fp32 out ----------------
__global__ __launch_bounds__(256, 1) void k_final(const u16* __restrict__ y,
                                                  const u16* __restrict__ Mt,
                                                  const float* __restrict__ xin,
                                                  const float* __restrict__ out_b,
                                                  float* __restrict__ out) {
  __shared__ u16 mt4[4 * 9216];  // 73728 B: Mt for fz=0..3
  __shared__ u16 vst[64 * 96];   // 12288 B: one column's v
  int tid = threadIdx.x;
  int b = blockIdx.x;
  int fxy = b >> 4, chunk = b & 15;
  int fx = fxy >> 2, fy = fxy & 3;
  int x = fx + 4 * chunk;
  const uint4* msrc = (const uint4*)(Mt + (size_t)(fx * 16 + fy * 4) * 9216);
  for (int i = tid; i < 4608; i += 256) ((uint4*)mt4)[i] = msrc[i];
  int vox = tid >> 2, qo = tid & 3, fz = vox & 3;
  float ob[24];
#pragma unroll
  for (int cc = 0; cc < 24; ++cc) ob[cc] = out_b[qo * 24 + cc];

  for (int m = 0; m < 16; ++m) {
    int yy = fy + 4 * m;
    size_t colvox = ((size_t)x * 64 + yy) * 64;
    __syncthreads();
    for (int i = tid; i < 768; i += 256) {
      int vv = i / 12, c8 = i - vv * 12;
      ((uint4*)vst)[vv * 12 + c8] =
          *(const uint4*)(y + (colvox + vv) * 288 + 192 + c8 * 8);
    }
    __syncthreads();
    float acc[24];
#pragma unroll
    for (int cc = 0; cc < 24; ++cc) acc[cc] = ob[cc];
    const u16* mslice = &mt4[fz * 9216 + qo * 24];
#pragma unroll 4
    for (int j = 0; j < 96; ++j) {
      float vj = bf2f(vst[vox * 96 + j]);
      const uint4* mq = (const uint4*)(mslice + j * 96);
      uint4 m0 = mq[0], m1 = mq[1], m2 = mq[2];
      uint32_t mw[12];
      *(uint4*)&mw[0] = m0; *(uint4*)&mw[4] = m1; *(uint4*)&mw[8] = m2;
#pragma unroll
      for (int i2 = 0; i2 < 12; ++i2) {
        union { uint32_t u; float f; } lo, hi;
        lo.u = mw[i2] << 16; hi.u = mw[i2] & 0xFFFF0000u;
        acc[2 * i2] += vj * lo.f;
        acc[2 * i2 + 1] += vj * hi.f;
      }
    }
    const float4* xs = (const float4*)(xin + (colvox + vox) * 96 + qo * 24);
    float4* op = (float4*)(out + (colvox + vox) * 96 + qo * 24);
#pragma unroll
    for (int i2 = 0; i2 < 6; ++i2) {
      float4 xv = xs[i2];
      float4 r;
      r.x = acc[4 * i2 + 0] + xv.x;
      r.y = acc[4 * i2 + 1] + xv.y;
      r.z = acc[4 * i2 + 2] + xv.z;
      r.w = acc[4 * i2 + 3] + xv.w;
      op[i2] = r;
    }
  }
}

extern "C" void kernel_launch(void* const* d_in, const int* in_sizes, int n_in,
                              void* d_out, int out_size, void* d_ws, size_t ws_size,
                              hipStream_t stream) {
  const float* x  = (const float*)d_in[0];
  const float* g  = (const float*)d_in[1];
  const float* be = (const float*)d_in[2];
  const float* qw = (const float*)d_in[3];
  const float* qb = (const float*)d_in[4];
  const float* ow = (const float*)d_in[5];
  const float* ob = (const float*)d_in[6];
  const float* tp = (const float*)d_in[7];
  float* out = (float*)d_out;

  // xn (bf16, 50.3 MB) lives in d_out scratch space; dead before k_final
  // overwrites d_out with the final fp32 result.
  u16* xn = (u16*)d_out;

  char* w = (char*)d_ws;
  u16* y    = (u16*)(w);                          // 150,994,944 B
  u16* Wb   = (u16*)(w + 150994944);              // 1,492,992 B
  float* S  = (float*)(w + 152487936);            // 589,824 B
  float* qn2 = (float*)(w + 153077760);           // 24,576 B
  float* kn2 = (float*)(w + 153102336);           // 24,576 B
  u16* Mt   = (u16*)(w + 153126912);              // 1,179,648 B (end ~154.3 MB)

  hipLaunchKernelGGL(k_ln, dim3(4096), dim3(256), 0, stream, x, g, be, xn);
  hipLaunchKernelGGL(k_repack, dim3((27 * 3 * 18 * 64 + 255) / 256), dim3(256), 0, stream, qw, Wb);
  hipLaunchKernelGGL(k_zero, dim3(624), dim3(256), 0, stream, S, 159744);
  hipLaunchKernelGGL(k_conv, dim3(4096), dim3(256), 0, stream, xn, Wb, qb, y);
  hipLaunchKernelGGL(k_gram, dim3(1024), dim3(256), 0, stream, y, S, qn2, kn2);
  hipLaunchKernelGGL(k_attn, dim3(64), dim3(256), 0, stream, S, qn2, kn2, ow, tp, Mt);
  hipLaunchKernelGGL(k_final, dim3(256), dim3(256), 0, stream, y, Mt, x, ob, out);
}

// Round 3
// 827.030 us; speedup vs baseline: 1.7256x; 1.7256x over previous
//
#include <hip/hip_runtime.h>
#include <stdint.h>

typedef unsigned short u16;
typedef float f32x4 __attribute__((ext_vector_type(4)));
typedef __bf16 v8bf __attribute__((ext_vector_type(8)));

static __device__ __forceinline__ float bf2f(u16 u) {
  union { uint32_t i; float f; } v; v.i = ((uint32_t)u) << 16; return v.f;
}
static __device__ __forceinline__ u16 f2bf(float f) {
  union { float f; uint32_t i; } v; v.f = f;
  uint32_t b = v.i;
  return (u16)((b + 0x7FFFu + ((b >> 16) & 1u)) >> 16);
}

// ---------------- K1: LayerNorm over C=96 (fp32 in) -> bf16 xn ----------------
__global__ __launch_bounds__(256) void k_ln(const float* __restrict__ x,
                                            const float* __restrict__ gamma,
                                            const float* __restrict__ beta,
                                            u16* __restrict__ xn) {
  int tid = threadIdx.x;
  int vox = blockIdx.x * 64 + (tid >> 2);
  int q = tid & 3;
  const float4* px = (const float4*)(x + (size_t)vox * 96 + q * 24);
  float f[24];
  *(float4*)&f[0]  = px[0]; *(float4*)&f[4]  = px[1]; *(float4*)&f[8]  = px[2];
  *(float4*)&f[12] = px[3]; *(float4*)&f[16] = px[4]; *(float4*)&f[20] = px[5];
  float s = 0.f, s2 = 0.f;
#pragma unroll
  for (int i = 0; i < 24; ++i) { s += f[i]; s2 += f[i] * f[i]; }
  s += __shfl_xor(s, 1);  s += __shfl_xor(s, 2);
  s2 += __shfl_xor(s2, 1); s2 += __shfl_xor(s2, 2);
  float mu = s * (1.f / 96.f);
  float var = s2 * (1.f / 96.f) - mu * mu;
  float rs = rsqrtf(var + 1e-5f);
  uint32_t ow[12];
#pragma unroll
  for (int i = 0; i < 12; ++i) {
    int c0 = q * 24 + 2 * i;
    float v0 = (f[2 * i]     - mu) * rs * gamma[c0]     + beta[c0];
    float v1 = (f[2 * i + 1] - mu) * rs * gamma[c0 + 1] + beta[c0 + 1];
    ow[i] = (uint32_t)f2bf(v0) | ((uint32_t)f2bf(v1) << 16);
  }
  uint4* po = (uint4*)(xn + (size_t)vox * 96 + q * 24);
  po[0] = *(uint4*)&ow[0]; po[1] = *(uint4*)&ow[4]; po[2] = *(uint4*)&ow[8];
}

// ---------------- K2: repack qkv_w (fp32) into bf16 MFMA B-fragment layout ----------------
// Wb[tap][ks][nt][lane][j] : value = W[tap][ci=ks*32+(lane>>4)*8+j][co=nt*16+(lane&15)]
__global__ __launch_bounds__(256) void k_repack(const float* __restrict__ qw,
                                                u16* __restrict__ Wb) {
  int t = blockIdx.x * 256 + threadIdx.x;
  if (t >= 27 * 3 * 18 * 64) return;
  int l = t & 63;
  int rest = t >> 6;
  int nt = rest % 18;
  int ks = (rest / 18) % 3;
  int tap = rest / 54;
  int co = nt * 16 + (l & 15);
  int cibase = ks * 32 + (l >> 4) * 8;
  u16 vals[8];
#pragma unroll
  for (int j = 0; j < 8; ++j)
    vals[j] = f2bf(qw[((size_t)tap * 96 + cibase + j) * 288 + co]);
  *(uint4*)(Wb + (size_t)t * 8) = *(uint4*)vals;
}

// ---------------- K0: zero scratch floats ----------------
__global__ __launch_bounds__(256) void k_zero(float* p, int n) {
  int i = blockIdx.x * 256 + threadIdx.x;
  if (i < n) p[i] = 0.f;
}

// ---------------- K3: conv3d 3x3x3 96->288 via MFMA bf16 ----------------
// Block = one (x0,y0) z-column of 64 voxels, all 288 out channels.
// A staged in LDS once per (dx,dy) with z-halo; B fragments read DIRECTLY
// from global (Wb is 1.5 MB, L2-hot; per-lane 16B reads are fully coalesced).
// No B staging -> no per-tap barriers; 18 barriers/block total.
__global__ __launch_bounds__(256, 3) void k_conv(const u16* __restrict__ xn,
                                                 const u16* __restrict__ Wb,
                                                 const float* __restrict__ qkvb,
                                                 u16* __restrict__ y) {
  __shared__ u16 As[66 * 104];     // 13,728 B; pitch 104 u16 = 52 dwords (2-way benign)
  int tid = threadIdx.x;
  // bijective XCD swizzle: 4096 blocks, 8 XCDs, 512 blocks/XCD -> each XCD
  // owns 8 consecutive x0 slabs (xn column reuse stays in one L2).
  int bid = blockIdx.x;
  int swz = (bid & 7) * 512 + (bid >> 3);
  int x0 = swz >> 6, y0 = swz & 63;
  int lane = tid & 63, w = tid >> 6;
  int wr = w >> 1, wc = w & 1;

  f32x4 acc[2][9];
#pragma unroll
  for (int m = 0; m < 2; ++m)
#pragma unroll
    for (int n = 0; n < 9; ++n) acc[m][n] = (f32x4)0.f;

  // wave-uniform base into Wb for this wave's N-half; per-lane 16B fragment
  const u16* wbase = Wb + (size_t)(wc * 9) * 64 * 8 + (size_t)lane * 8;

  for (int dxy = 0; dxy < 9; ++dxy) {
    int dx = dxy / 3, dy = dxy % 3;
    int xx = x0 + dx - 1, yy = y0 + dy - 1;
    bool colok = ((unsigned)xx < 64u) && ((unsigned)yy < 64u);
    __syncthreads();
    {
      const uint4* src = (const uint4*)(xn + ((size_t)(xx * 64 + yy) * 64) * 96);
      for (int i = tid; i < 66 * 12; i += 256) {
        int row = i / 12, c8 = i - row * 12;
        uint4 v = make_uint4(0u, 0u, 0u, 0u);
        if (colok && row >= 1 && row <= 64) v = src[(row - 1) * 12 + c8];
        *(uint4*)&As[row * 104 + c8 * 8] = v;
      }
    }
    __syncthreads();

#pragma unroll
    for (int dz = 0; dz < 3; ++dz) {
      int tap = dxy * 3 + dz;
#pragma unroll
      for (int ks = 0; ks < 3; ++ks) {
        int ar = wr * 32 + (lane & 15) + dz;
        int ac = ks * 32 + (lane >> 4) * 8;
        v8bf a0 = *(const v8bf*)&As[ar * 104 + ac];
        v8bf a1 = *(const v8bf*)&As[(ar + 16) * 104 + ac];
        const u16* bptr = wbase + (size_t)(tap * 3 + ks) * (18 * 64 * 8);
#pragma unroll
        for (int nt = 0; nt < 9; ++nt) {
          v8bf b = *(const v8bf*)(bptr + (size_t)nt * (64 * 8));
          acc[0][nt] = __builtin_amdgcn_mfma_f32_16x16x32_bf16(a0, b, acc[0][nt], 0, 0, 0);
          acc[1][nt] = __builtin_amdgcn_mfma_f32_16x16x32_bf16(a1, b, acc[1][nt], 0, 0, 0);
        }
      }
    }
  }

  size_t voxbase = (size_t)(x0 * 64 + y0) * 64;
#pragma unroll
  for (int m = 0; m < 2; ++m)
#pragma unroll
    for (int nt = 0; nt < 9; ++nt) {
      int col = wc * 144 + nt * 16 + (lane & 15);
      float bias = qkvb[col];
#pragma unroll
      for (int r = 0; r < 4; ++r) {
        int vrow = wr * 32 + m * 16 + (lane >> 4) * 4 + r;
        y[(voxbase + vrow) * 288 + col] = f2bf(acc[m][nt][r] + bias);
      }
    }
}

// ---------------- K4: Gram S[f,h,c,d] = sum_g q.k, plus norms ----------------
__global__ __launch_bounds__(256) void k_gram(const u16* __restrict__ y,
                                              float* __restrict__ S,
                                              float* __restrict__ qn2,
                                              float* __restrict__ kn2) {
  __shared__ u16 qk[8 * 192];
  int tid = threadIdx.x;
  int f = blockIdx.x >> 4, chunk = blockIdx.x & 15;
  int fx = f >> 4, fy = (f >> 2) & 3, fz = f & 3;
  int h = tid >> 6;
  int e0 = tid * 9;
  int ci[9], di[9];
#pragma unroll
  for (int i = 0; i < 9; ++i) {
    int rem = (e0 + i) % 576;
    ci[i] = rem / 24; di[i] = rem % 24;
  }
  float cacc[9];
#pragma unroll
  for (int i = 0; i < 9; ++i) cacc[i] = 0.f;
  float nacc = 0.f;

  for (int grp = 0; grp < 32; ++grp) {
    __syncthreads();
    for (int i = tid; i < 192; i += 256) {
      int rr = i / 24, c8 = i - rr * 24;
      int g = chunk * 256 + grp * 8 + rr;
      int gx = g >> 8, gy = (g >> 4) & 15, gz = g & 15;
      size_t vox = ((size_t)(gx * 4 + fx) * 64 + (gy * 4 + fy)) * 64 + (gz * 4 + fz);
      *(uint4*)&qk[rr * 192 + c8 * 8] = *(const uint4*)(y + vox * 288 + c8 * 8);
    }
    __syncthreads();
#pragma unroll 2
    for (int r = 0; r < 8; ++r) {
      const u16* row = &qk[r * 192];
#pragma unroll
      for (int i = 0; i < 9; ++i) {
        float qv = bf2f(row[h * 24 + ci[i]]);
        float kv = bf2f(row[96 + h * 24 + di[i]]);
        cacc[i] += qv * kv;
      }
      if (tid < 192) { float v = bf2f(row[tid]); nacc += v * v; }
    }
  }
  float* Sf = S + (size_t)f * 2304;
#pragma unroll
  for (int i = 0; i < 9; ++i) atomicAdd(&Sf[e0 + i], cacc[i]);
  if (tid < 96) atomicAdd(&qn2[f * 96 + tid], nacc);
  else if (tid < 192) atomicAdd(&kn2[f * 96 + tid - 96], nacc);
}

// ---------------- K5: normalize + softmax + fold out_w -> Mt[f][j][c'] (bf16) ----------------
__global__ __launch_bounds__(256) void k_attn(const float* __restrict__ S,
                                              const float* __restrict__ qn2,
                                              const float* __restrict__ kn2,
                                              const float* __restrict__ out_w,
                                              const float* __restrict__ temp,
                                              u16* __restrict__ Mt) {
  __shared__ float attn[2304];
  __shared__ float invq[96], invk[96];
  __shared__ float ow[9216];
  int tid = threadIdx.x;
  int f = blockIdx.x;
  if (tid < 96) {
    invq[tid] = 1.f / fmaxf(sqrtf(qn2[f * 96 + tid]), 1e-12f);
    invk[tid] = 1.f / fmaxf(sqrtf(kn2[f * 96 + tid]), 1e-12f);
  }
  for (int i = tid; i < 9216; i += 256) ow[i] = out_w[i];
  __syncthreads();
  if (tid < 96) {
    int h = tid / 24, c = tid % 24;
    float tmp = temp[h];
    const float* Sr = S + (size_t)f * 2304 + (size_t)h * 576 + c * 24;
    float lg[24];
    float mx = -1e30f;
#pragma unroll
    for (int d = 0; d < 24; ++d) {
      lg[d] = Sr[d] * invq[tid] * invk[h * 24 + d] * tmp;
      mx = fmaxf(mx, lg[d]);
    }
    float sum = 0.f;
#pragma unroll
    for (int d = 0; d < 24; ++d) { lg[d] = __expf(lg[d] - mx); sum += lg[d]; }
    float inv = 1.f / sum;
#pragma unroll
    for (int d = 0; d < 24; ++d) attn[h * 576 + c * 24 + d] = lg[d] * inv;
  }
  __syncthreads();
  for (int o = tid; o < 9216; o += 256) {
    int j = o / 96, cp = o - j * 96;
    int h2 = j / 24, d = j % 24;
    float s = 0.f;
#pragma unroll
    for (int cc = 0; cc < 24; ++cc)
      s += attn[h2 * 576 + cc * 24 + d] * ow[cp * 96 + h2 * 24 + cc];
    Mt[(size_t)f * 9216 + o] = f2bf(s);
  }
}

// ---------------- K6: out = Mt[f] @ v + out_b + x (residual), fp32 out ----------------
__global__ __launch_bounds__(256, 1) void k_final(const u16* __restrict__ y,
                                                  const u16* __restrict__ Mt,
                                                  const float* __restrict__ xin,
                                                  const float* __restrict__ out_b,
                                                  float* __restrict__ out) {
  __shared__ u16 mt4[4 * 9216];  // 73728 B: Mt for fz=0..3
  __shared__ u16 vst[64 * 96];   // 12288 B: one column's v
  int tid = threadIdx.x;
  int b = blockIdx.x;
  int fxy = b >> 4, chunk = b & 15;
  int fx = fxy >> 2, fy = fxy & 3;
  int x = fx + 4 * chunk;
  const uint4* msrc = (const uint4*)(Mt + (size_t)(fx * 16 + fy * 4) * 9216);
  for (int i = tid; i < 4608; i += 256) ((uint4*)mt4)[i] = msrc[i];
  int vox = tid >> 2, qo = tid & 3, fz = vox & 3;
  float ob[24];
#pragma unroll
  for (int cc = 0; cc < 24; ++cc) ob[cc] = out_b[qo * 24 + cc];

  for (int m = 0; m < 16; ++m) {
    int yy = fy + 4 * m;
    size_t colvox = ((size_t)x * 64 + yy) * 64;
    __syncthreads();
    for (int i = tid; i < 768; i += 256) {
      int vv = i / 12, c8 = i - vv * 12;
      ((uint4*)vst)[vv * 12 + c8] =
          *(const uint4*)(y + (colvox + vv) * 288 + 192 + c8 * 8);
    }
    __syncthreads();
    float acc[24];
#pragma unroll
    for (int cc = 0; cc < 24; ++cc) acc[cc] = ob[cc];
    const u16* mslice = &mt4[fz * 9216 + qo * 24];
#pragma unroll 4
    for (int j = 0; j < 96; ++j) {
      float vj = bf2f(vst[vox * 96 + j]);
      const uint4* mq = (const uint4*)(mslice + j * 96);
      uint4 m0 = mq[0], m1 = mq[1], m2 = mq[2];
      uint32_t mw[12];
      *(uint4*)&mw[0] = m0; *(uint4*)&mw[4] = m1; *(uint4*)&mw[8] = m2;
#pragma unroll
      for (int i2 = 0; i2 < 12; ++i2) {
        union { uint32_t u; float f; } lo, hi;
        lo.u = mw[i2] << 16; hi.u = mw[i2] & 0xFFFF0000u;
        acc[2 * i2] += vj * lo.f;
        acc[2 * i2 + 1] += vj * hi.f;
      }
    }
    const float4* xs = (const float4*)(xin + (colvox + vox) * 96 + qo * 24);
    float4* op = (float4*)(out + (colvox + vox) * 96 + qo * 24);
#pragma unroll
    for (int i2 = 0; i2 < 6; ++i2) {
      float4 xv = xs[i2];
      float4 r;
      r.x = acc[4 * i2 + 0] + xv.x;
      r.y = acc[4 * i2 + 1] + xv.y;
      r.z = acc[4 * i2 + 2] + xv.z;
      r.w = acc[4 * i2 + 3] + xv.w;
      op[i2] = r;
    }
  }
}

extern "C" void kernel_launch(void* const* d_in, const int* in_sizes, int n_in,
                              void* d_out, int out_size, void* d_ws, size_t ws_size,
                              hipStream_t stream) {
  const float* x  = (const float*)d_in[0];
  const float* g  = (const float*)d_in[1];
  const float* be = (const float*)d_in[2];
  const float* qw = (const float*)d_in[3];
  const float* qb = (const float*)d_in[4];
  const float* ow = (const float*)d_in[5];
  const float* ob = (const float*)d_in[6];
  const float* tp = (const float*)d_in[7];
  float* out = (float*)d_out;

  // xn (bf16, 50.3 MB) lives in d_out scratch space; dead before k_final
  // overwrites d_out with the final fp32 result.
  u16* xn = (u16*)d_out;

  char* w = (char*)d_ws;
  u16* y    = (u16*)(w);                          // 150,994,944 B
  u16* Wb   = (u16*)(w + 150994944);              // 1,492,992 B
  float* S  = (float*)(w + 152487936);            // 589,824 B
  float* qn2 = (float*)(w + 153077760);           // 24,576 B
  float* kn2 = (float*)(w + 153102336);           // 24,576 B
  u16* Mt   = (u16*)(w + 153126912);              // 1,179,648 B (end ~154.3 MB)

  hipLaunchKernelGGL(k_ln, dim3(4096), dim3(256), 0, stream, x, g, be, xn);
  hipLaunchKernelGGL(k_repack, dim3((27 * 3 * 18 * 64 + 255) / 256), dim3(256), 0, stream, qw, Wb);
  hipLaunchKernelGGL(k_zero, dim3(624), dim3(256), 0, stream, S, 159744);
  hipLaunchKernelGGL(k_conv, dim3(4096), dim3(256), 0, stream, xn, Wb, qb, y);
  hipLaunchKernelGGL(k_gram, dim3(1024), dim3(256), 0, stream, y, S, qn2, kn2);
  hipLaunchKernelGGL(k_attn, dim3(64), dim3(256), 0, stream, S, qn2, kn2, ow, tp, Mt);
  hipLaunchKernelGGL(k_final, dim3(256), dim3(256), 0, stream, y, Mt, x, ob, out);
}